// Round 1
// baseline (830.573 us; speedup 1.0000x reference)
//
#include <hip/hip_runtime.h>
#include <math.h>

#define N_NODES 100000
#define N_EDGESI 1600000
#define E_TOTAL (N_EDGESI + N_NODES)
#define N_GRAPHS 2000
#define F_IN 16
#define HEADS 8
#define CPH 16
#define HC 128
#define NEG 0.2f

__device__ __forceinline__ float leaky(float x){ return fmaxf(x, NEG*x); }

// ---------- CSR build ----------
__global__ void k_count(const int* __restrict__ ei, int* __restrict__ cnt){
  int e = blockIdx.x*256 + threadIdx.x;
  if (e >= E_TOTAL) return;
  int d = (e < N_EDGESI) ? ei[N_EDGESI + e] : (e - N_EDGESI);
  atomicAdd(&cnt[d], 1);
}

// single-block exclusive scan: 1024 threads, 4 items/thread per chunk
__global__ void k_scan(const int* __restrict__ cnt, int* __restrict__ off){
  __shared__ int wsum[16];
  int t = threadIdx.x; int lane = t & 63; int wv = t >> 6;
  int carry = 0;
  for (int base = 0; base < N_NODES; base += 4096){
    int i0 = base + t*4;
    int v[4];
    #pragma unroll
    for (int q=0;q<4;++q){ int i = i0+q; v[q] = (i<N_NODES)?cnt[i]:0; }
    int tsum = v[0]+v[1]+v[2]+v[3];
    int sc = tsum;
    #pragma unroll
    for (int o=1;o<64;o<<=1){ int u = __shfl_up(sc, o, 64); if (lane >= o) sc += u; }
    if (lane==63) wsum[wv] = sc;
    __syncthreads();
    if (wv==0 && lane<16){
      int ws = wsum[lane];
      #pragma unroll
      for (int o=1;o<16;o<<=1){ int u = __shfl_up(ws,o,64); if (lane>=o) ws += u; }
      wsum[lane] = ws;
    }
    __syncthreads();
    int wpre = (wv==0)?0:wsum[wv-1];
    int excl = carry + wpre + (sc - tsum);
    #pragma unroll
    for (int q=0;q<4;++q){ int i=i0+q; if (i<N_NODES) off[i] = excl; excl += v[q]; }
    int tot = wsum[15];
    __syncthreads();
    carry += tot;
  }
  if (t==0) off[N_NODES] = carry;
}

__global__ void k_copy(const int* __restrict__ off, int* __restrict__ cur){
  int i = blockIdx.x*256+threadIdx.x;
  if (i < N_NODES) cur[i] = off[i];
}

__global__ void k_scatter(const int* __restrict__ ei, int* __restrict__ cur, int* __restrict__ csrc){
  int e = blockIdx.x*256 + threadIdx.x;
  if (e >= E_TOTAL) return;
  int s, d;
  if (e < N_EDGESI){ s = ei[e]; d = ei[N_EDGESI + e]; }
  else { s = d = e - N_EDGESI; }
  int p = atomicAdd(&cur[d], 1);
  csrc[p] = s;
}

// ---------- layer GEMMs ----------
__global__ void k_gemm1(const float* __restrict__ x, const float* __restrict__ W, float* __restrict__ hf){
  int i = blockIdx.x*256 + threadIdx.x;
  if (i >= N_NODES*HC) return;
  int n = i >> 7, c = i & 127;
  const float* xr = x + n*F_IN;
  float acc = 0.f;
  #pragma unroll
  for (int k = 0; k < F_IN; ++k) acc += xr[k]*W[k*HC + c];
  hf[i] = acc;
}

__global__ void k_gemm2(const float* __restrict__ hin, const float* __restrict__ W, float* __restrict__ hf){
  __shared__ float xs[8*HC];
  int t = threadIdx.x;
  int n0 = blockIdx.x*8;
  for (int i = t; i < 8*HC; i += 256){
    int n = n0 + (i>>7);
    xs[i] = (n < N_NODES) ? hin[n*HC + (i&127)] : 0.f;
  }
  __syncthreads();
  int c = t & 127, jb = t >> 7;
  float acc[4] = {0.f,0.f,0.f,0.f};
  for (int k = 0; k < HC; ++k){
    float wv = W[k*HC + c];
    #pragma unroll
    for (int q = 0; q < 4; ++q) acc[q] += xs[(jb + 2*q)*HC + k]*wv;
  }
  #pragma unroll
  for (int q = 0; q < 4; ++q){
    int n = n0 + jb + 2*q;
    if (n < N_NODES) hf[n*HC + c] = acc[q];
  }
}

__global__ void k_logits(const float* __restrict__ hf, const float* __restrict__ asrc,
                         const float* __restrict__ adst, float* __restrict__ ls, float* __restrict__ ld){
  int i = blockIdx.x*256 + threadIdx.x;   // n*8+h
  if (i >= N_NODES*HEADS) return;
  int h = i & 7;
  const float* hr = hf + (size_t)(i>>3)*HC + h*CPH;
  const float* as = asrc + h*CPH;
  const float* ad = adst + h*CPH;
  float s0=0.f, s1=0.f;
  #pragma unroll
  for (int c = 0; c < CPH; ++c){ float v = hr[c]; s0 += v*as[c]; s1 += v*ad[c]; }
  ls[i] = s0; ld[i] = s1;
}

// ---------- attention + aggregation: one wave per destination node ----------
__global__ void k_agg(const int* __restrict__ off, const int* __restrict__ csrc,
                      const float* __restrict__ hf, const float* __restrict__ ls,
                      const float* __restrict__ ld, const float* __restrict__ bias,
                      float* __restrict__ out){
  int wid = threadIdx.x >> 6, lane = threadIdx.x & 63;
  int n = blockIdx.x*4 + wid;
  if (n >= N_NODES) return;
  int rs = __builtin_amdgcn_readfirstlane(off[n]);
  int re = __builtin_amdgcn_readfirstlane(off[n+1]);
  int h = lane >> 3;                       // my head (2 channels per lane, same head)
  const float4* ld4 = (const float4*)(ld + n*8);
  float4 l0 = ld4[0], l1 = ld4[1];
  float ldall[8] = {l0.x,l0.y,l0.z,l0.w,l1.x,l1.y,l1.z,l1.w};
  float m8[8];
  #pragma unroll
  for (int j=0;j<8;++j) m8[j] = -INFINITY;
  // pass A: per-head max over incoming edges (lane-strided)
  for (int e = rs + lane; e < re; e += 64){
    int s = csrc[e];
    const float4* ls4 = (const float4*)(ls + s*8);
    float4 a = ls4[0], b = ls4[1];
    float sv[8] = {a.x,a.y,a.z,a.w,b.x,b.y,b.z,b.w};
    #pragma unroll
    for (int j=0;j<8;++j) m8[j] = fmaxf(m8[j], leaky(sv[j] + ldall[j]));
  }
  #pragma unroll
  for (int o = 32; o >= 1; o >>= 1){
    #pragma unroll
    for (int j=0;j<8;++j) m8[j] = fmaxf(m8[j], __shfl_xor(m8[j], o, 64));
  }
  float mh = m8[0];
  #pragma unroll
  for (int j=1;j<8;++j) mh = (h==j) ? m8[j] : mh;
  float ldh = ldall[0];
  #pragma unroll
  for (int j=1;j<8;++j) ldh = (h==j) ? ldall[j] : ldh;
  // pass B: serial over edges; every lane sees every edge so dsum is complete
  float acc0=0.f, acc1=0.f, dsum=0.f;
  const float2* hf2 = (const float2*)hf;
  for (int e = rs; e < re; ++e){
    int s = __builtin_amdgcn_readfirstlane(csrc[e]);
    float ex = __expf(leaky(ls[s*8+h] + ldh) - mh);
    float2 hv = hf2[(size_t)s*64 + lane];
    acc0 += ex*hv.x; acc1 += ex*hv.y; dsum += ex;
  }
  float inv = 1.f/fmaxf(dsum, 1e-16f);
  int c0 = lane*2;
  float o0 = fmaxf(acc0*inv + bias[c0],   0.f);
  float o1 = fmaxf(acc1*inv + bias[c0+1], 0.f);
  ((float2*)out)[(size_t)n*64 + lane] = make_float2(o0, o1);
}

// ---------- pooling + classify ----------
__global__ void k_pool(const float* __restrict__ h, const int* __restrict__ batch,
                       float* __restrict__ pooled, float* __restrict__ gcnt){
  int i = blockIdx.x*256 + threadIdx.x;
  if (i >= N_NODES*HC) return;
  int n = i >> 7, c = i & 127;
  int g = batch[n];
  atomicAdd(&pooled[g*HC + c], h[i]);
  if (c == 0) atomicAdd(&gcnt[g], 1.f);
}

__global__ void k_cls(const float* __restrict__ pooled, const float* __restrict__ gcnt,
                      const float* __restrict__ lw, const float* __restrict__ lb,
                      float* __restrict__ out){
  int g = blockIdx.x; int lane = threadIdx.x;  // 64 threads
  float invc = 1.f/fmaxf(gcnt[g], 1.f);
  float2 p = ((const float2*)(pooled + g*HC))[lane];
  float v0 = p.x*invc, v1 = p.y*invc;
  int k0 = lane*2;
  float l0 = v0*lw[k0*2+0] + v1*lw[(k0+1)*2+0];
  float l1 = v0*lw[k0*2+1] + v1*lw[(k0+1)*2+1];
  #pragma unroll
  for (int o = 32; o >= 1; o >>= 1){ l0 += __shfl_xor(l0,o,64); l1 += __shfl_xor(l1,o,64); }
  if (lane == 0){
    l0 += lb[0]; l1 += lb[1];
    float m = fmaxf(l0,l1);
    float e0 = __expf(l0-m), e1 = __expf(l1-m);
    float s = e0+e1;
    out[g*2]   = e0/s;
    out[g*2+1] = e1/s;
  }
}

extern "C" void kernel_launch(void* const* d_in, const int* in_sizes, int n_in,
                              void* d_out, int out_size, void* d_ws, size_t ws_size,
                              hipStream_t stream){
  const float* x   = (const float*)d_in[0];
  const int*   ei  = (const int*)d_in[1];
  const int*   bat = (const int*)d_in[2];
  const float* W1  = (const float*)d_in[3];
  const float* a1s = (const float*)d_in[4];
  const float* a1d = (const float*)d_in[5];
  const float* b1  = (const float*)d_in[6];
  const float* W2  = (const float*)d_in[7];
  const float* a2s = (const float*)d_in[8];
  const float* a2d = (const float*)d_in[9];
  const float* b2  = (const float*)d_in[10];
  const float* lw  = (const float*)d_in[11];
  const float* lb  = (const float*)d_in[12];
  float* out = (float*)d_out;

  char* w = (char*)d_ws;
  auto alloc = [&](size_t bytes)->void*{ void* p = (void*)w; w += (bytes + 511) & ~size_t(511); return p; };
  int* cnt    = (int*)alloc((size_t)N_NODES*4);
  int* off    = (int*)alloc((size_t)(N_NODES+1)*4);
  int* cur    = (int*)alloc((size_t)N_NODES*4);
  int* csrc   = (int*)alloc((size_t)E_TOTAL*4);
  float* hfeat= (float*)alloc((size_t)N_NODES*HC*4);
  float* hbuf = (float*)alloc((size_t)N_NODES*HC*4);
  float* lsb  = (float*)alloc((size_t)N_NODES*HEADS*4);
  float* ldb  = (float*)alloc((size_t)N_NODES*HEADS*4);
  float* pooled=(float*)alloc((size_t)N_GRAPHS*HC*4);
  float* gcnt = (float*)alloc((size_t)N_GRAPHS*4);

  hipMemsetAsync(cnt, 0, (size_t)N_NODES*4, stream);
  hipMemsetAsync(pooled, 0, (size_t)N_GRAPHS*HC*4, stream);
  hipMemsetAsync(gcnt, 0, (size_t)N_GRAPHS*4, stream);

  int eb = (E_TOTAL + 255)/256;
  k_count  <<<eb,256,0,stream>>>(ei, cnt);
  k_scan   <<<1,1024,0,stream>>>(cnt, off);
  k_copy   <<<(N_NODES+255)/256,256,0,stream>>>(off, cur);
  k_scatter<<<eb,256,0,stream>>>(ei, cur, csrc);

  // layer 1
  k_gemm1 <<<(N_NODES*HC+255)/256,256,0,stream>>>(x, W1, hfeat);
  k_logits<<<(N_NODES*HEADS+255)/256,256,0,stream>>>(hfeat, a1s, a1d, lsb, ldb);
  k_agg   <<<(N_NODES+3)/4,256,0,stream>>>(off, csrc, hfeat, lsb, ldb, b1, hbuf);
  // layer 2
  k_gemm2 <<<(N_NODES+7)/8,256,0,stream>>>(hbuf, W2, hfeat);
  k_logits<<<(N_NODES*HEADS+255)/256,256,0,stream>>>(hfeat, a2s, a2d, lsb, ldb);
  k_agg   <<<(N_NODES+3)/4,256,0,stream>>>(off, csrc, hfeat, lsb, ldb, b2, hbuf);

  // pooling + classifier
  k_pool<<<(N_NODES*HC+255)/256,256,0,stream>>>(hbuf, bat, pooled, gcnt);
  k_cls <<<N_GRAPHS,64,0,stream>>>(pooled, gcnt, lw, lb, out);
}

// Round 2
// 530.569 us; speedup vs baseline: 1.5654x; 1.5654x over previous
//
#include <hip/hip_runtime.h>
#include <math.h>

#define N_NODES 100000
#define N_EDGESI 1600000
#define E_TOTAL (N_EDGESI + N_NODES)
#define N_GRAPHS 2000
#define F_IN 16
#define HEADS 8
#define CPH 16
#define HC 128
#define NEG 0.2f
#define SCAN_B 1024
#define NB_SCAN ((N_NODES + SCAN_B - 1)/SCAN_B)   // 98

__device__ __forceinline__ float leaky(float x){ return fmaxf(x, NEG*x); }
__device__ __forceinline__ float bf2f(unsigned short u){ return __uint_as_float(((unsigned)u)<<16); }
__device__ __forceinline__ unsigned short f2bf(float f){
  unsigned u = __float_as_uint(f);
  unsigned r = (u + 0x7fffu + ((u>>16)&1u)) >> 16;
  return (unsigned short)r;
}
__device__ __forceinline__ float blo(unsigned u){ return __uint_as_float(u<<16); }
__device__ __forceinline__ float bhi(unsigned u){ return __uint_as_float(u & 0xffff0000u); }

// ---------- CSR build ----------
__global__ void k_count(const int* __restrict__ ei, int* __restrict__ cnt){
  int e = blockIdx.x*256 + threadIdx.x;
  if (e >= E_TOTAL) return;
  int d = (e < N_EDGESI) ? ei[N_EDGESI + e] : (e - N_EDGESI);
  atomicAdd(&cnt[d], 1);
}

__global__ void k_scan1(const int* __restrict__ cnt, int* __restrict__ off, int* __restrict__ bsum){
  __shared__ int ws[16];
  int b = blockIdx.x, t = threadIdx.x, lane = t & 63, wv = t >> 6;
  int i = b*SCAN_B + t;
  int v = (i < N_NODES) ? cnt[i] : 0;
  int sc = v;
  #pragma unroll
  for (int o=1;o<64;o<<=1){ int u = __shfl_up(sc, o, 64); if (lane >= o) sc += u; }
  if (lane==63) ws[wv] = sc;
  __syncthreads();
  if (wv==0 && lane<16){
    int w = ws[lane];
    #pragma unroll
    for (int o=1;o<16;o<<=1){ int u = __shfl_up(w,o,64); if (lane>=o) w += u; }
    ws[lane] = w;
  }
  __syncthreads();
  int base = wv ? ws[wv-1] : 0;
  if (i < N_NODES) off[i] = base + sc - v;
  if (t == SCAN_B-1) bsum[b] = ws[15];
}

__global__ void k_scan2(int* __restrict__ bsum, int nb){
  __shared__ int ws[4];
  int t = threadIdx.x, lane = t & 63, wv = t >> 6;   // 256 threads
  int v = (t < nb) ? bsum[t] : 0;
  int sc = v;
  #pragma unroll
  for (int o=1;o<64;o<<=1){ int u = __shfl_up(sc,o,64); if (lane>=o) sc += u; }
  if (lane==63) ws[wv] = sc;
  __syncthreads();
  if (wv==0 && lane<4){
    int w = ws[lane];
    #pragma unroll
    for (int o=1;o<4;o<<=1){ int u = __shfl_up(w,o,64); if (lane>=o) w += u; }
    ws[lane] = w;
  }
  __syncthreads();
  int base = wv ? ws[wv-1] : 0;
  int excl = base + sc - v;
  int total = ws[3];
  __syncthreads();
  if (t < nb) bsum[t] = excl;
  if (t == nb) bsum[nb] = total;
}

__global__ void k_scan3(int* __restrict__ off, const int* __restrict__ bsum, int* __restrict__ cur){
  int i = blockIdx.x*256 + threadIdx.x;
  if (i < N_NODES){
    int v = off[i] + bsum[i>>10];
    off[i] = v; cur[i] = v;
  }
  if (i == 0) off[N_NODES] = bsum[NB_SCAN];
}

__global__ void k_scatter(const int* __restrict__ ei, int* __restrict__ cur, int* __restrict__ csrc){
  int e = blockIdx.x*256 + threadIdx.x;
  if (e >= E_TOTAL) return;
  int s, d;
  if (e < N_EDGESI){ s = ei[e]; d = ei[N_EDGESI + e]; }
  else { s = d = e - N_EDGESI; }
  int p = atomicAdd(&cur[d], 1);
  csrc[p] = s;
}

// graph offsets from sorted batch
__global__ void k_goff(const int* __restrict__ batch, int* __restrict__ goff){
  int n = blockIdx.x*256 + threadIdx.x;
  if (n >= N_NODES) return;
  int b = batch[n];
  if (n == 0){ for (int g = 0; g <= b; ++g) goff[g] = 0; }
  int b1 = (n+1 < N_NODES) ? batch[n+1] : N_GRAPHS;
  for (int g = b+1; g <= b1; ++g) goff[g] = n+1;
}

// ---------- layer GEMMs (bf16 h output) ----------
__global__ void k_gemm1(const float* __restrict__ x, const float* __restrict__ W,
                        unsigned short* __restrict__ hb){
  int i = blockIdx.x*256 + threadIdx.x;          // n*64 + cpair
  if (i >= N_NODES*64) return;
  int n = i >> 6, cp = i & 63;
  const float* xr = x + n*F_IN;
  const float2* W2v = (const float2*)W;
  float a0 = 0.f, a1 = 0.f;
  #pragma unroll
  for (int k = 0; k < F_IN; ++k){
    float xv = xr[k];
    float2 w = W2v[k*64 + cp];
    a0 += xv*w.x; a1 += xv*w.y;
  }
  ushort2 o; o.x = f2bf(a0); o.y = f2bf(a1);
  ((ushort2*)hb)[i] = o;
}

__global__ void k_gemm2(const float* __restrict__ hin, const float* __restrict__ W,
                        unsigned short* __restrict__ hb){
  __shared__ float xs[16*HC];
  int t = threadIdx.x;
  int n0 = blockIdx.x*16;
  for (int q = t; q < 512; q += 256){
    int n = n0 + (q>>5);
    float4 z = make_float4(0.f,0.f,0.f,0.f);
    ((float4*)xs)[q] = (n < N_NODES) ? ((const float4*)(hin + (size_t)n*HC))[q&31] : z;
  }
  __syncthreads();
  int c = t & 127, gsel = t >> 7;
  const float* xb = xs + gsel*8*HC;
  float acc[8] = {0,0,0,0,0,0,0,0};
  for (int k4 = 0; k4 < 32; ++k4){
    float w0 = W[(k4*4+0)*HC + c];
    float w1 = W[(k4*4+1)*HC + c];
    float w2 = W[(k4*4+2)*HC + c];
    float w3 = W[(k4*4+3)*HC + c];
    #pragma unroll
    for (int j = 0; j < 8; ++j){
      float4 xv = ((const float4*)(xb + j*HC))[k4];
      acc[j] += xv.x*w0 + xv.y*w1 + xv.z*w2 + xv.w*w3;
    }
  }
  #pragma unroll
  for (int j = 0; j < 8; ++j){
    int n = n0 + gsel*8 + j;
    if (n < N_NODES) hb[(size_t)n*HC + c] = f2bf(acc[j]);
  }
}

// ---------- per-node attention half-logits from bf16 h ----------
__global__ void k_logits(const unsigned short* __restrict__ hb, const float* __restrict__ asrc,
                         const float* __restrict__ adst, float* __restrict__ ls, float* __restrict__ ld){
  int i = blockIdx.x*256 + threadIdx.x;   // n*8+h
  if (i >= N_NODES*HEADS) return;
  int h = i & 7;
  const uint4* p = (const uint4*)(hb + (size_t)(i>>3)*HC + h*CPH);
  uint4 A = p[0], B = p[1];
  const float* as = asrc + h*CPH;
  const float* ad = adst + h*CPH;
  float c[16] = { blo(A.x), bhi(A.x), blo(A.y), bhi(A.y), blo(A.z), bhi(A.z), blo(A.w), bhi(A.w),
                  blo(B.x), bhi(B.x), blo(B.y), bhi(B.y), blo(B.z), bhi(B.z), blo(B.w), bhi(B.w) };
  float s0 = 0.f, s1 = 0.f;
  #pragma unroll
  for (int q = 0; q < 16; ++q){ s0 += c[q]*as[q]; s1 += c[q]*ad[q]; }
  ls[i] = s0; ld[i] = s1;
}

// ---------- attention + aggregation: one wave per destination node ----------
__global__ void k_agg(const int* __restrict__ off, const int* __restrict__ csrc,
                      const unsigned short* __restrict__ hb, const float* __restrict__ ls,
                      const float* __restrict__ ld, const float* __restrict__ bias,
                      float* __restrict__ out){
  int wid = threadIdx.x >> 6, lane = threadIdx.x & 63;
  int n = blockIdx.x*4 + wid;
  if (n >= N_NODES) return;
  int rs = __builtin_amdgcn_readfirstlane(off[n]);
  int re = __builtin_amdgcn_readfirstlane(off[n+1]);
  int h = lane >> 3;
  float ldh = ld[n*8 + h];
  const ushort2* hb2 = (const ushort2*)hb;
  float acc0 = 0.f, acc1 = 0.f, dsum = 0.f;
  int e = rs;
  for (; e + 4 <= re; e += 4){
    int s0 = __builtin_amdgcn_readfirstlane(csrc[e+0]);
    int s1 = __builtin_amdgcn_readfirstlane(csrc[e+1]);
    int s2 = __builtin_amdgcn_readfirstlane(csrc[e+2]);
    int s3 = __builtin_amdgcn_readfirstlane(csrc[e+3]);
    float g0 = ls[s0*8+h], g1 = ls[s1*8+h], g2 = ls[s2*8+h], g3 = ls[s3*8+h];
    ushort2 v0 = hb2[(size_t)s0*64 + lane];
    ushort2 v1 = hb2[(size_t)s1*64 + lane];
    ushort2 v2 = hb2[(size_t)s2*64 + lane];
    ushort2 v3 = hb2[(size_t)s3*64 + lane];
    float x0 = __expf(leaky(g0 + ldh));
    float x1 = __expf(leaky(g1 + ldh));
    float x2 = __expf(leaky(g2 + ldh));
    float x3 = __expf(leaky(g3 + ldh));
    acc0 += x0*bf2f(v0.x); acc1 += x0*bf2f(v0.y);
    acc0 += x1*bf2f(v1.x); acc1 += x1*bf2f(v1.y);
    acc0 += x2*bf2f(v2.x); acc1 += x2*bf2f(v2.y);
    acc0 += x3*bf2f(v3.x); acc1 += x3*bf2f(v3.y);
    dsum += x0 + x1 + x2 + x3;
  }
  for (; e < re; ++e){
    int s = __builtin_amdgcn_readfirstlane(csrc[e]);
    float ex = __expf(leaky(ls[s*8+h] + ldh));
    ushort2 v = hb2[(size_t)s*64 + lane];
    acc0 += ex*bf2f(v.x); acc1 += ex*bf2f(v.y);
    dsum += ex;
  }
  float inv = 1.f/fmaxf(dsum, 1e-16f);
  int c0 = lane*2;
  float o0 = fmaxf(acc0*inv + bias[c0],   0.f);
  float o1 = fmaxf(acc1*inv + bias[c0+1], 0.f);
  ((float2*)out)[(size_t)n*64 + lane] = make_float2(o0, o1);
}

// ---------- pooling + classify fused: one block per graph ----------
__global__ void k_poolcls(const float* __restrict__ h, const int* __restrict__ goff,
                          const float* __restrict__ lw, const float* __restrict__ lb,
                          float* __restrict__ out){
  __shared__ float sh[4][HC];
  int g = blockIdx.x;
  int t = threadIdx.x, lane = t & 63, wv = t >> 6;
  int s = goff[g], epos = goff[g+1];
  float a0 = 0.f, a1 = 0.f;
  for (int n = s + wv; n < epos; n += 4){
    float2 v = ((const float2*)h)[(size_t)n*64 + lane];
    a0 += v.x; a1 += v.y;
  }
  sh[wv][lane*2] = a0; sh[wv][lane*2+1] = a1;
  __syncthreads();
  if (wv == 0){
    int c0 = lane*2;
    float p0 = sh[0][c0] + sh[1][c0] + sh[2][c0] + sh[3][c0];
    float p1 = sh[0][c0+1] + sh[1][c0+1] + sh[2][c0+1] + sh[3][c0+1];
    int cntg = epos - s;
    float invc = 1.f/fmaxf((float)cntg, 1.f);
    float v0 = p0*invc, v1 = p1*invc;
    float l0 = v0*lw[c0*2+0] + v1*lw[(c0+1)*2+0];
    float l1 = v0*lw[c0*2+1] + v1*lw[(c0+1)*2+1];
    #pragma unroll
    for (int o = 32; o >= 1; o >>= 1){ l0 += __shfl_xor(l0,o,64); l1 += __shfl_xor(l1,o,64); }
    if (lane == 0){
      l0 += lb[0]; l1 += lb[1];
      float m = fmaxf(l0,l1);
      float e0 = __expf(l0-m), e1 = __expf(l1-m);
      float si = e0 + e1;
      out[g*2]   = e0/si;
      out[g*2+1] = e1/si;
    }
  }
}

extern "C" void kernel_launch(void* const* d_in, const int* in_sizes, int n_in,
                              void* d_out, int out_size, void* d_ws, size_t ws_size,
                              hipStream_t stream){
  const float* x   = (const float*)d_in[0];
  const int*   ei  = (const int*)d_in[1];
  const int*   bat = (const int*)d_in[2];
  const float* W1  = (const float*)d_in[3];
  const float* a1s = (const float*)d_in[4];
  const float* a1d = (const float*)d_in[5];
  const float* b1  = (const float*)d_in[6];
  const float* W2  = (const float*)d_in[7];
  const float* a2s = (const float*)d_in[8];
  const float* a2d = (const float*)d_in[9];
  const float* b2  = (const float*)d_in[10];
  const float* lw  = (const float*)d_in[11];
  const float* lb  = (const float*)d_in[12];
  float* out = (float*)d_out;

  char* w = (char*)d_ws;
  auto alloc = [&](size_t bytes)->void*{ void* p = (void*)w; w += (bytes + 511) & ~size_t(511); return p; };
  int* cnt    = (int*)alloc((size_t)N_NODES*4);
  int* off    = (int*)alloc((size_t)(N_NODES+1)*4);
  int* cur    = (int*)alloc((size_t)N_NODES*4);
  int* csrc   = (int*)alloc((size_t)E_TOTAL*4);
  int* bsum   = (int*)alloc((size_t)(NB_SCAN+1)*4);
  int* goff   = (int*)alloc((size_t)(N_GRAPHS+1)*4);
  unsigned short* hbf = (unsigned short*)alloc((size_t)N_NODES*HC*2);
  float* hbuf = (float*)alloc((size_t)N_NODES*HC*4);
  float* lsb  = (float*)alloc((size_t)N_NODES*HEADS*4);
  float* ldb  = (float*)alloc((size_t)N_NODES*HEADS*4);

  hipMemsetAsync(cnt, 0, (size_t)N_NODES*4, stream);

  int eb = (E_TOTAL + 255)/256;
  k_count <<<eb,256,0,stream>>>(ei, cnt);
  k_scan1 <<<NB_SCAN,SCAN_B,0,stream>>>(cnt, off, bsum);
  k_scan2 <<<1,256,0,stream>>>(bsum, NB_SCAN);
  k_scan3 <<<(N_NODES+255)/256,256,0,stream>>>(off, bsum, cur);
  k_scatter<<<eb,256,0,stream>>>(ei, cur, csrc);
  k_goff  <<<(N_NODES+255)/256,256,0,stream>>>(bat, goff);

  // layer 1
  k_gemm1 <<<(N_NODES*64+255)/256,256,0,stream>>>(x, W1, hbf);
  k_logits<<<(N_NODES*HEADS+255)/256,256,0,stream>>>(hbf, a1s, a1d, lsb, ldb);
  k_agg   <<<(N_NODES+3)/4,256,0,stream>>>(off, csrc, hbf, lsb, ldb, b1, hbuf);
  // layer 2
  k_gemm2 <<<(N_NODES+15)/16,256,0,stream>>>(hbuf, W2, hbf);
  k_logits<<<(N_NODES*HEADS+255)/256,256,0,stream>>>(hbf, a2s, a2d, lsb, ldb);
  k_agg   <<<(N_NODES+3)/4,256,0,stream>>>(off, csrc, hbf, lsb, ldb, b2, hbuf);

  // pooling + classifier
  k_poolcls<<<N_GRAPHS,256,0,stream>>>(hbuf, goff, lw, lb, out);
}

// Round 3
// 387.715 us; speedup vs baseline: 2.1422x; 1.3685x over previous
//
#include <hip/hip_runtime.h>
#include <math.h>

#define N_NODES 100000
#define N_EDGESI 1600000
#define E_TOTAL (N_EDGESI + N_NODES)
#define N_GRAPHS 2000
#define F_IN 16
#define HEADS 8
#define CPH 16
#define HC 128
#define NEG 0.2f
#define SCAN_B 1024
#define NB_SCAN ((N_NODES + SCAN_B - 1)/SCAN_B)   // 98

// bucketed scatter params
#define BSHIFT 9
#define BNODES (1<<BSHIFT)                         // 512 nodes per bucket
#define NBUK ((N_NODES + BNODES - 1)/BNODES)       // 196
#define BCAP 12288                                 // entries per bucket (mean ~8700, sigma ~93)
#define BIN_EPT 16
#define BIN_TPB 256
#define BIN_EPB (BIN_EPT*BIN_TPB)                  // 4096
#define NBIN_BLK ((E_TOTAL + BIN_EPB - 1)/BIN_EPB) // 416

__device__ __forceinline__ float leaky(float x){ return fmaxf(x, NEG*x); }
__device__ __forceinline__ float bf2f(unsigned short u){ return __uint_as_float(((unsigned)u)<<16); }
__device__ __forceinline__ unsigned short f2bf(float f){
  unsigned u = __float_as_uint(f);
  unsigned r = (u + 0x7fffu + ((u>>16)&1u)) >> 16;
  return (unsigned short)r;
}
__device__ __forceinline__ float blo(unsigned u){ return __uint_as_float(u<<16); }
__device__ __forceinline__ float bhi(unsigned u){ return __uint_as_float(u & 0xffff0000u); }

// ---------- phase 1: bin edges by destination range ----------
__global__ void k_bin(const int* __restrict__ ei, int* __restrict__ gpos, unsigned* __restrict__ gbin){
  __shared__ unsigned bcnt[NBUK];
  __shared__ unsigned bbase[NBUK];
  int t = threadIdx.x;
  for (int i = t; i < NBUK; i += BIN_TPB) bcnt[i] = 0;
  __syncthreads();
  int base = blockIdx.x*BIN_EPB;
  unsigned entry[BIN_EPT]; unsigned meta[BIN_EPT];   // meta = rank<<8 | bucket
  #pragma unroll
  for (int i = 0; i < BIN_EPT; ++i){
    int e = base + i*BIN_TPB + t;
    if (e < E_TOTAL){
      unsigned s, d;
      if (e < N_EDGESI){ s = (unsigned)ei[e]; d = (unsigned)ei[N_EDGESI + e]; }
      else { s = d = (unsigned)(e - N_EDGESI); }
      unsigned b = d >> BSHIFT;
      unsigned r = atomicAdd(&bcnt[b], 1u);
      entry[i] = ((d & (BNODES-1u)) << 17) | s;
      meta[i] = (r << 8) | b;
    } else meta[i] = 0xffffffffu;
  }
  __syncthreads();
  for (int i = t; i < NBUK; i += BIN_TPB) bbase[i] = (unsigned)atomicAdd(&gpos[i], (int)bcnt[i]);
  __syncthreads();
  #pragma unroll
  for (int i = 0; i < BIN_EPT; ++i){
    if (meta[i] != 0xffffffffu){
      unsigned b = meta[i] & 0xffu;
      unsigned r = meta[i] >> 8;
      gbin[(size_t)b*BCAP + bbase[b] + r] = entry[i];
    }
  }
}

// ---------- phase 2a: per-node counts (no global atomics) ----------
__global__ void k_bcnt(const int* __restrict__ gpos, const unsigned* __restrict__ gbin,
                       int* __restrict__ cnt){
  __shared__ int lc[BNODES];
  int b = blockIdx.x, t = threadIdx.x;
  for (int i = t; i < BNODES; i += 256) lc[i] = 0;
  __syncthreads();
  int nb = gpos[b];
  const unsigned* bb = gbin + (size_t)b*BCAP;
  for (int i = t; i < nb; i += 256) atomicAdd(&lc[bb[i] >> 17], 1);
  __syncthreads();
  int d0 = b << BSHIFT;
  for (int i = t; i < BNODES; i += 256){
    int d = d0 + i;
    if (d < N_NODES) cnt[d] = lc[i];
  }
}

// ---------- scan ----------
__global__ void k_scan1(const int* __restrict__ cnt, int* __restrict__ off, int* __restrict__ bsum){
  __shared__ int ws[16];
  int b = blockIdx.x, t = threadIdx.x, lane = t & 63, wv = t >> 6;
  int i = b*SCAN_B + t;
  int v = (i < N_NODES) ? cnt[i] : 0;
  int sc = v;
  #pragma unroll
  for (int o=1;o<64;o<<=1){ int u = __shfl_up(sc, o, 64); if (lane >= o) sc += u; }
  if (lane==63) ws[wv] = sc;
  __syncthreads();
  if (wv==0 && lane<16){
    int w = ws[lane];
    #pragma unroll
    for (int o=1;o<16;o<<=1){ int u = __shfl_up(w,o,64); if (lane>=o) w += u; }
    ws[lane] = w;
  }
  __syncthreads();
  int base = wv ? ws[wv-1] : 0;
  if (i < N_NODES) off[i] = base + sc - v;
  if (t == SCAN_B-1) bsum[b] = ws[15];
}

__global__ void k_scan2(int* __restrict__ bsum, int nb){
  __shared__ int ws[4];
  int t = threadIdx.x, lane = t & 63, wv = t >> 6;
  int v = (t < nb) ? bsum[t] : 0;
  int sc = v;
  #pragma unroll
  for (int o=1;o<64;o<<=1){ int u = __shfl_up(sc,o,64); if (lane>=o) sc += u; }
  if (lane==63) ws[wv] = sc;
  __syncthreads();
  if (wv==0 && lane<4){
    int w = ws[lane];
    #pragma unroll
    for (int o=1;o<4;o<<=1){ int u = __shfl_up(w,o,64); if (lane>=o) w += u; }
    ws[lane] = w;
  }
  __syncthreads();
  int base = wv ? ws[wv-1] : 0;
  int excl = base + sc - v;
  int total = ws[3];
  __syncthreads();
  if (t < nb) bsum[t] = excl;
  if (t == nb) bsum[nb] = total;
}

__global__ void k_scan3(int* __restrict__ off, const int* __restrict__ bsum){
  int i = blockIdx.x*256 + threadIdx.x;
  if (i < N_NODES) off[i] += bsum[i>>10];
  if (i == 0) off[N_NODES] = bsum[NB_SCAN];
}

// ---------- phase 2b: scatter within buckets (LDS cursors) ----------
__global__ void k_bscatter(const int* __restrict__ gpos, const unsigned* __restrict__ gbin,
                           const int* __restrict__ off, int* __restrict__ csrc){
  __shared__ int lcur[BNODES];
  int b = blockIdx.x, t = threadIdx.x;
  int d0 = b << BSHIFT;
  for (int i = t; i < BNODES; i += 256){
    int d = d0 + i;
    lcur[i] = (d < N_NODES) ? off[d] : 0;
  }
  __syncthreads();
  int nb = gpos[b];
  const unsigned* bb = gbin + (size_t)b*BCAP;
  for (int i = t; i < nb; i += 256){
    unsigned en = bb[i];
    int p = atomicAdd(&lcur[en >> 17], 1);
    csrc[p] = (int)(en & 0x1ffffu);
  }
}

// graph offsets from sorted batch
__global__ void k_goff(const int* __restrict__ batch, int* __restrict__ goff){
  int n = blockIdx.x*256 + threadIdx.x;
  if (n >= N_NODES) return;
  int b = batch[n];
  if (n == 0){ for (int g = 0; g <= b; ++g) goff[g] = 0; }
  int b1 = (n+1 < N_NODES) ? batch[n+1] : N_GRAPHS;
  for (int g = b+1; g <= b1; ++g) goff[g] = n+1;
}

// ---------- layer GEMMs ----------
__global__ void k_gemm1(const float* __restrict__ x, const float* __restrict__ W,
                        unsigned short* __restrict__ hb){
  int i = blockIdx.x*256 + threadIdx.x;          // n*64 + cpair
  if (i >= N_NODES*64) return;
  int n = i >> 6, cp = i & 63;
  const float* xr = x + n*F_IN;
  const float2* W2v = (const float2*)W;
  float a0 = 0.f, a1 = 0.f;
  #pragma unroll
  for (int k = 0; k < F_IN; ++k){
    float xv = xr[k];
    float2 w = W2v[k*64 + cp];
    a0 += xv*w.x; a1 += xv*w.y;
  }
  ushort2 o; o.x = f2bf(a0); o.y = f2bf(a1);
  ((ushort2*)hb)[i] = o;
}

// bf16 input GEMM: hin [N,128] bf16, W f32, out bf16
__global__ void k_gemm2(const unsigned short* __restrict__ hin, const float* __restrict__ W,
                        unsigned short* __restrict__ hb){
  __shared__ float xs[16*HC];
  int t = threadIdx.x;
  int n0 = blockIdx.x*16;
  for (int q = t; q < 512; q += 256){                 // q: row=q>>5, 4-chan group=q&31
    int n = n0 + (q>>5);
    float4 v = make_float4(0.f,0.f,0.f,0.f);
    if (n < N_NODES){
      uint2 u = ((const uint2*)(hin + (size_t)n*HC))[q&31];
      v = make_float4(blo(u.x), bhi(u.x), blo(u.y), bhi(u.y));
    }
    ((float4*)xs)[q] = v;
  }
  __syncthreads();
  int c = t & 127, gsel = t >> 7;
  const float* xb = xs + gsel*8*HC;
  float acc[8] = {0,0,0,0,0,0,0,0};
  for (int k4 = 0; k4 < 32; ++k4){
    float w0 = W[(k4*4+0)*HC + c];
    float w1 = W[(k4*4+1)*HC + c];
    float w2 = W[(k4*4+2)*HC + c];
    float w3 = W[(k4*4+3)*HC + c];
    #pragma unroll
    for (int j = 0; j < 8; ++j){
      float4 xv = ((const float4*)(xb + j*HC))[k4];
      acc[j] += xv.x*w0 + xv.y*w1 + xv.z*w2 + xv.w*w3;
    }
  }
  #pragma unroll
  for (int j = 0; j < 8; ++j){
    int n = n0 + gsel*8 + j;
    if (n < N_NODES) hb[(size_t)n*HC + c] = f2bf(acc[j]);
  }
}

// ---------- per-node attention half-logits from bf16 h ----------
__global__ void k_logits(const unsigned short* __restrict__ hb, const float* __restrict__ asrc,
                         const float* __restrict__ adst, float* __restrict__ ls, float* __restrict__ ld){
  int i = blockIdx.x*256 + threadIdx.x;   // n*8+h
  if (i >= N_NODES*HEADS) return;
  int h = i & 7;
  const uint4* p = (const uint4*)(hb + (size_t)(i>>3)*HC + h*CPH);
  uint4 A = p[0], B = p[1];
  const float* as = asrc + h*CPH;
  const float* ad = adst + h*CPH;
  float c[16] = { blo(A.x), bhi(A.x), blo(A.y), bhi(A.y), blo(A.z), bhi(A.z), blo(A.w), bhi(A.w),
                  blo(B.x), bhi(B.x), blo(B.y), bhi(B.y), blo(B.z), bhi(B.z), blo(B.w), bhi(B.w) };
  float s0 = 0.f, s1 = 0.f;
  #pragma unroll
  for (int q = 0; q < 16; ++q){ s0 += c[q]*as[q]; s1 += c[q]*ad[q]; }
  ls[i] = s0; ld[i] = s1;
}

// ---------- attention + aggregation: one wave per destination node ----------
template<bool OBF>
__global__ void k_agg(const int* __restrict__ off, const int* __restrict__ csrc,
                      const unsigned short* __restrict__ hb, const float* __restrict__ ls,
                      const float* __restrict__ ld, const float* __restrict__ bias,
                      void* __restrict__ outv){
  int wid = threadIdx.x >> 6, lane = threadIdx.x & 63;
  int n = blockIdx.x*4 + wid;
  if (n >= N_NODES) return;
  int rs = __builtin_amdgcn_readfirstlane(off[n]);
  int re = __builtin_amdgcn_readfirstlane(off[n+1]);
  int h = lane >> 3;
  float ldh = ld[n*8 + h];
  const ushort2* hb2 = (const ushort2*)hb;
  float acc0 = 0.f, acc1 = 0.f, dsum = 0.f;
  int e = rs;
  for (; e + 4 <= re; e += 4){
    int s0 = __builtin_amdgcn_readfirstlane(csrc[e+0]);
    int s1 = __builtin_amdgcn_readfirstlane(csrc[e+1]);
    int s2 = __builtin_amdgcn_readfirstlane(csrc[e+2]);
    int s3 = __builtin_amdgcn_readfirstlane(csrc[e+3]);
    float g0 = ls[s0*8+h], g1 = ls[s1*8+h], g2 = ls[s2*8+h], g3 = ls[s3*8+h];
    ushort2 v0 = hb2[(size_t)s0*64 + lane];
    ushort2 v1 = hb2[(size_t)s1*64 + lane];
    ushort2 v2 = hb2[(size_t)s2*64 + lane];
    ushort2 v3 = hb2[(size_t)s3*64 + lane];
    float x0 = __expf(leaky(g0 + ldh));
    float x1 = __expf(leaky(g1 + ldh));
    float x2 = __expf(leaky(g2 + ldh));
    float x3 = __expf(leaky(g3 + ldh));
    acc0 += x0*bf2f(v0.x); acc1 += x0*bf2f(v0.y);
    acc0 += x1*bf2f(v1.x); acc1 += x1*bf2f(v1.y);
    acc0 += x2*bf2f(v2.x); acc1 += x2*bf2f(v2.y);
    acc0 += x3*bf2f(v3.x); acc1 += x3*bf2f(v3.y);
    dsum += x0 + x1 + x2 + x3;
  }
  for (; e < re; ++e){
    int s = __builtin_amdgcn_readfirstlane(csrc[e]);
    float ex = __expf(leaky(ls[s*8+h] + ldh));
    ushort2 v = hb2[(size_t)s*64 + lane];
    acc0 += ex*bf2f(v.x); acc1 += ex*bf2f(v.y);
    dsum += ex;
  }
  float inv = 1.f/fmaxf(dsum, 1e-16f);
  int c0 = lane*2;
  float o0 = fmaxf(acc0*inv + bias[c0],   0.f);
  float o1 = fmaxf(acc1*inv + bias[c0+1], 0.f);
  if (OBF){
    ushort2 o; o.x = f2bf(o0); o.y = f2bf(o1);
    ((ushort2*)outv)[(size_t)n*64 + lane] = o;
  } else {
    ((float2*)outv)[(size_t)n*64 + lane] = make_float2(o0, o1);
  }
}

// ---------- pooling + classify fused: one block per graph ----------
__global__ void k_poolcls(const float* __restrict__ h, const int* __restrict__ goff,
                          const float* __restrict__ lw, const float* __restrict__ lb,
                          float* __restrict__ out){
  __shared__ float sh[4][HC];
  int g = blockIdx.x;
  int t = threadIdx.x, lane = t & 63, wv = t >> 6;
  int s = goff[g], epos = goff[g+1];
  float a0 = 0.f, a1 = 0.f;
  for (int n = s + wv; n < epos; n += 4){
    float2 v = ((const float2*)h)[(size_t)n*64 + lane];
    a0 += v.x; a1 += v.y;
  }
  sh[wv][lane*2] = a0; sh[wv][lane*2+1] = a1;
  __syncthreads();
  if (wv == 0){
    int c0 = lane*2;
    float p0 = sh[0][c0] + sh[1][c0] + sh[2][c0] + sh[3][c0];
    float p1 = sh[0][c0+1] + sh[1][c0+1] + sh[2][c0+1] + sh[3][c0+1];
    int cntg = epos - s;
    float invc = 1.f/fmaxf((float)cntg, 1.f);
    float v0 = p0*invc, v1 = p1*invc;
    float l0 = v0*lw[c0*2+0] + v1*lw[(c0+1)*2+0];
    float l1 = v0*lw[c0*2+1] + v1*lw[(c0+1)*2+1];
    #pragma unroll
    for (int o = 32; o >= 1; o >>= 1){ l0 += __shfl_xor(l0,o,64); l1 += __shfl_xor(l1,o,64); }
    if (lane == 0){
      l0 += lb[0]; l1 += lb[1];
      float m = fmaxf(l0,l1);
      float e0 = __expf(l0-m), e1 = __expf(l1-m);
      float si = e0 + e1;
      out[g*2]   = e0/si;
      out[g*2+1] = e1/si;
    }
  }
}

extern "C" void kernel_launch(void* const* d_in, const int* in_sizes, int n_in,
                              void* d_out, int out_size, void* d_ws, size_t ws_size,
                              hipStream_t stream){
  const float* x   = (const float*)d_in[0];
  const int*   ei  = (const int*)d_in[1];
  const int*   bat = (const int*)d_in[2];
  const float* W1  = (const float*)d_in[3];
  const float* a1s = (const float*)d_in[4];
  const float* a1d = (const float*)d_in[5];
  const float* b1  = (const float*)d_in[6];
  const float* W2  = (const float*)d_in[7];
  const float* a2s = (const float*)d_in[8];
  const float* a2d = (const float*)d_in[9];
  const float* b2  = (const float*)d_in[10];
  const float* lw  = (const float*)d_in[11];
  const float* lb  = (const float*)d_in[12];
  float* out = (float*)d_out;

  char* w = (char*)d_ws;
  auto alloc = [&](size_t bytes)->void*{ void* p = (void*)w; w += (bytes + 511) & ~size_t(511); return p; };
  int* cnt    = (int*)alloc((size_t)N_NODES*4);
  int* off    = (int*)alloc((size_t)(N_NODES+1)*4);
  int* csrc   = (int*)alloc((size_t)E_TOTAL*4);
  int* bsum   = (int*)alloc((size_t)(NB_SCAN+1)*4);
  int* goff   = (int*)alloc((size_t)(N_GRAPHS+1)*4);
  int* gpos   = (int*)alloc((size_t)NBUK*4);
  unsigned short* hbf  = (unsigned short*)alloc((size_t)N_NODES*HC*2);
  unsigned short* hbf2 = (unsigned short*)alloc((size_t)N_NODES*HC*2);
  float* hbuf = (float*)alloc((size_t)N_NODES*HC*4);       // also aliased as gbin during CSR build
  float* lsb  = (float*)alloc((size_t)N_NODES*HEADS*4);
  float* ldb  = (float*)alloc((size_t)N_NODES*HEADS*4);
  unsigned* gbin = (unsigned*)hbuf;                        // 196*12288*4 = 9.6 MB < 51.2 MB

  hipMemsetAsync(gpos, 0, (size_t)NBUK*4, stream);

  // CSR build (bucketed)
  k_bin     <<<NBIN_BLK,BIN_TPB,0,stream>>>(ei, gpos, gbin);
  k_bcnt    <<<NBUK,256,0,stream>>>(gpos, gbin, cnt);
  k_scan1   <<<NB_SCAN,SCAN_B,0,stream>>>(cnt, off, bsum);
  k_scan2   <<<1,256,0,stream>>>(bsum, NB_SCAN);
  k_scan3   <<<(N_NODES+255)/256,256,0,stream>>>(off, bsum);
  k_bscatter<<<NBUK,256,0,stream>>>(gpos, gbin, off, csrc);
  k_goff    <<<(N_NODES+255)/256,256,0,stream>>>(bat, goff);

  // layer 1
  k_gemm1 <<<(N_NODES*64+255)/256,256,0,stream>>>(x, W1, hbf);
  k_logits<<<(N_NODES*HEADS+255)/256,256,0,stream>>>(hbf, a1s, a1d, lsb, ldb);
  k_agg<true> <<<(N_NODES+3)/4,256,0,stream>>>(off, csrc, hbf, lsb, ldb, b1, (void*)hbf2);
  // layer 2
  k_gemm2 <<<(N_NODES+15)/16,256,0,stream>>>(hbf2, W2, hbf);
  k_logits<<<(N_NODES*HEADS+255)/256,256,0,stream>>>(hbf, a2s, a2d, lsb, ldb);
  k_agg<false><<<(N_NODES+3)/4,256,0,stream>>>(off, csrc, hbf, lsb, ldb, b2, (void*)hbuf);

  // pooling + classifier
  k_poolcls<<<N_GRAPHS,256,0,stream>>>(hbuf, goff, lw, lb, out);
}

// Round 4
// 347.391 us; speedup vs baseline: 2.3909x; 1.1161x over previous
//
#include <hip/hip_runtime.h>
#include <math.h>

#define N_NODES 100000
#define N_EDGESI 1600000
#define E_TOTAL (N_EDGESI + N_NODES)
#define N_GRAPHS 2000
#define F_IN 16
#define HEADS 8
#define CPH 16
#define HC 128
#define NEG 0.2f
#define SCAN_B 1024
#define NB_SCAN ((N_NODES + SCAN_B - 1)/SCAN_B)   // 98

// bucketed scatter params
#define BSHIFT 9
#define BNODES (1<<BSHIFT)                         // 512 nodes per bucket
#define NBUK ((N_NODES + BNODES - 1)/BNODES)       // 196
#define BCAP 12288
#define BIN_EPT 16
#define BIN_TPB 256
#define BIN_EPB (BIN_EPT*BIN_TPB)                  // 4096
#define NBIN_BLK ((E_TOTAL + BIN_EPB - 1)/BIN_EPB) // 416

typedef __bf16 bf16x8 __attribute__((ext_vector_type(8)));
typedef float  f32x4  __attribute__((ext_vector_type(4)));

__device__ __forceinline__ float leaky(float x){ return fmaxf(x, NEG*x); }
__device__ __forceinline__ float bf2f(unsigned short u){ return __uint_as_float(((unsigned)u)<<16); }
__device__ __forceinline__ unsigned short f2bf(float f){
  unsigned u = __float_as_uint(f);
  unsigned r = (u + 0x7fffu + ((u>>16)&1u)) >> 16;
  return (unsigned short)r;
}
__device__ __forceinline__ float blo(unsigned u){ return __uint_as_float(u<<16); }
__device__ __forceinline__ float bhi(unsigned u){ return __uint_as_float(u & 0xffff0000u); }

// ---------- phase 1: bin edges by destination range ----------
__global__ void k_bin(const int* __restrict__ ei, int* __restrict__ gpos, unsigned* __restrict__ gbin){
  __shared__ unsigned bcnt[NBUK];
  __shared__ unsigned bbase[NBUK];
  int t = threadIdx.x;
  for (int i = t; i < NBUK; i += BIN_TPB) bcnt[i] = 0;
  __syncthreads();
  int base = blockIdx.x*BIN_EPB;
  unsigned entry[BIN_EPT]; unsigned meta[BIN_EPT];   // meta = rank<<8 | bucket
  #pragma unroll
  for (int i = 0; i < BIN_EPT; ++i){
    int e = base + i*BIN_TPB + t;
    if (e < E_TOTAL){
      unsigned s, d;
      if (e < N_EDGESI){ s = (unsigned)ei[e]; d = (unsigned)ei[N_EDGESI + e]; }
      else { s = d = (unsigned)(e - N_EDGESI); }
      unsigned b = d >> BSHIFT;
      unsigned r = atomicAdd(&bcnt[b], 1u);
      entry[i] = ((d & (BNODES-1u)) << 17) | s;
      meta[i] = (r << 8) | b;
    } else meta[i] = 0xffffffffu;
  }
  __syncthreads();
  for (int i = t; i < NBUK; i += BIN_TPB) bbase[i] = (unsigned)atomicAdd(&gpos[i], (int)bcnt[i]);
  __syncthreads();
  #pragma unroll
  for (int i = 0; i < BIN_EPT; ++i){
    if (meta[i] != 0xffffffffu){
      unsigned b = meta[i] & 0xffu;
      unsigned r = meta[i] >> 8;
      gbin[(size_t)b*BCAP + bbase[b] + r] = entry[i];
    }
  }
}

// ---------- phase 2a: per-node counts ----------
__global__ void k_bcnt(const int* __restrict__ gpos, const unsigned* __restrict__ gbin,
                       int* __restrict__ cnt){
  __shared__ int lc[BNODES];
  int b = blockIdx.x, t = threadIdx.x;
  for (int i = t; i < BNODES; i += 256) lc[i] = 0;
  __syncthreads();
  int nb = gpos[b];
  const unsigned* bb = gbin + (size_t)b*BCAP;
  for (int i = t; i < nb; i += 256) atomicAdd(&lc[bb[i] >> 17], 1);
  __syncthreads();
  int d0 = b << BSHIFT;
  for (int i = t; i < BNODES; i += 256){
    int d = d0 + i;
    if (d < N_NODES) cnt[d] = lc[i];
  }
}

// ---------- scan ----------
__global__ void k_scan1(const int* __restrict__ cnt, int* __restrict__ off, int* __restrict__ bsum){
  __shared__ int ws[16];
  int b = blockIdx.x, t = threadIdx.x, lane = t & 63, wv = t >> 6;
  int i = b*SCAN_B + t;
  int v = (i < N_NODES) ? cnt[i] : 0;
  int sc = v;
  #pragma unroll
  for (int o=1;o<64;o<<=1){ int u = __shfl_up(sc, o, 64); if (lane >= o) sc += u; }
  if (lane==63) ws[wv] = sc;
  __syncthreads();
  if (wv==0 && lane<16){
    int w = ws[lane];
    #pragma unroll
    for (int o=1;o<16;o<<=1){ int u = __shfl_up(w,o,64); if (lane>=o) w += u; }
    ws[lane] = w;
  }
  __syncthreads();
  int base = wv ? ws[wv-1] : 0;
  if (i < N_NODES) off[i] = base + sc - v;
  if (t == SCAN_B-1) bsum[b] = ws[15];
}

__global__ void k_scan2(int* __restrict__ bsum, int nb){
  __shared__ int ws[4];
  int t = threadIdx.x, lane = t & 63, wv = t >> 6;
  int v = (t < nb) ? bsum[t] : 0;
  int sc = v;
  #pragma unroll
  for (int o=1;o<64;o<<=1){ int u = __shfl_up(sc,o,64); if (lane>=o) sc += u; }
  if (lane==63) ws[wv] = sc;
  __syncthreads();
  if (wv==0 && lane<4){
    int w = ws[lane];
    #pragma unroll
    for (int o=1;o<4;o<<=1){ int u = __shfl_up(w,o,64); if (lane>=o) w += u; }
    ws[lane] = w;
  }
  __syncthreads();
  int base = wv ? ws[wv-1] : 0;
  int excl = base + sc - v;
  int total = ws[3];
  __syncthreads();
  if (t < nb) bsum[t] = excl;
  if (t == nb) bsum[nb] = total;
}

__global__ void k_scan3(int* __restrict__ off, const int* __restrict__ bsum){
  int i = blockIdx.x*256 + threadIdx.x;
  if (i < N_NODES) off[i] += bsum[i>>10];
  if (i == 0) off[N_NODES] = bsum[NB_SCAN];
}

// ---------- phase 2b: scatter within buckets ----------
__global__ void k_bscatter(const int* __restrict__ gpos, const unsigned* __restrict__ gbin,
                           const int* __restrict__ off, int* __restrict__ csrc){
  __shared__ int lcur[BNODES];
  int b = blockIdx.x, t = threadIdx.x;
  int d0 = b << BSHIFT;
  for (int i = t; i < BNODES; i += 256){
    int d = d0 + i;
    lcur[i] = (d < N_NODES) ? off[d] : 0;
  }
  __syncthreads();
  int nb = gpos[b];
  const unsigned* bb = gbin + (size_t)b*BCAP;
  for (int i = t; i < nb; i += 256){
    unsigned en = bb[i];
    int p = atomicAdd(&lcur[en >> 17], 1);
    csrc[p] = (int)(en & 0x1ffffu);
  }
}

// graph offsets from sorted batch
__global__ void k_goff(const int* __restrict__ batch, int* __restrict__ goff){
  int n = blockIdx.x*256 + threadIdx.x;
  if (n >= N_NODES) return;
  int b = batch[n];
  if (n == 0){ for (int g = 0; g <= b; ++g) goff[g] = 0; }
  int b1 = (n+1 < N_NODES) ? batch[n+1] : N_GRAPHS;
  for (int g = b+1; g <= b1; ++g) goff[g] = n+1;
}

// ---------- layer 1 GEMM (VALU, K=16) ----------
__global__ void k_gemm1(const float* __restrict__ x, const float* __restrict__ W,
                        unsigned short* __restrict__ hb){
  int i = blockIdx.x*256 + threadIdx.x;          // n*64 + cpair
  if (i >= N_NODES*64) return;
  int n = i >> 6, cp = i & 63;
  const float* xr = x + n*F_IN;
  const float2* W2v = (const float2*)W;
  float a0 = 0.f, a1 = 0.f;
  #pragma unroll
  for (int k = 0; k < F_IN; ++k){
    float xv = xr[k];
    float2 w = W2v[k*64 + cp];
    a0 += xv*w.x; a1 += xv*w.y;
  }
  ushort2 o; o.x = f2bf(a0); o.y = f2bf(a1);
  ((ushort2*)hb)[i] = o;
}

// ---------- W2 -> bf16 transposed [c][k] ----------
__global__ void k_wconv(const float* __restrict__ W, unsigned short* __restrict__ Wt){
  int i = blockIdx.x*256 + threadIdx.x;  // c*128 + k
  if (i >= HC*HC) return;
  int c = i >> 7, k = i & 127;
  Wt[i] = f2bf(W[k*HC + c]);
}

// ---------- layer 2 GEMM via MFMA bf16 ----------
// wave: 16 rows x 128 cols; block: 4 waves = 64 rows
__global__ void k_gemm2_mfma(const unsigned short* __restrict__ hin,
                             const unsigned short* __restrict__ w2t,
                             unsigned short* __restrict__ hb){
  int t = threadIdx.x, lane = t & 63, wv = t >> 6;
  int n0 = blockIdx.x*64 + wv*16;
  int rowl = lane & 15, kgrp = lane >> 4;
  int row = n0 + rowl;
  int rowc = (row < N_NODES) ? row : (N_NODES-1);
  bf16x8 a[4];
  #pragma unroll
  for (int ks = 0; ks < 4; ++ks)
    a[ks] = *(const bf16x8*)(hin + (size_t)rowc*HC + ks*32 + kgrp*8);
  #pragma unroll
  for (int ct = 0; ct < 8; ++ct){
    f32x4 acc = {0.f, 0.f, 0.f, 0.f};
    int col = ct*16 + rowl;
    #pragma unroll
    for (int ks = 0; ks < 4; ++ks){
      bf16x8 b = *(const bf16x8*)(w2t + (size_t)col*HC + ks*32 + kgrp*8);
      acc = __builtin_amdgcn_mfma_f32_16x16x32_bf16(a[ks], b, acc, 0, 0, 0);
    }
    #pragma unroll
    for (int r = 0; r < 4; ++r){
      int ro = n0 + kgrp*4 + r;
      if (ro < N_NODES) hb[(size_t)ro*HC + col] = f2bf(acc[r]);
    }
  }
}

// ---------- per-node attention half-logits from bf16 h ----------
__global__ void k_logits(const unsigned short* __restrict__ hb, const float* __restrict__ asrc,
                         const float* __restrict__ adst, float* __restrict__ ls, float* __restrict__ ld){
  int i = blockIdx.x*256 + threadIdx.x;   // n*8+h
  if (i >= N_NODES*HEADS) return;
  int h = i & 7;
  const uint4* p = (const uint4*)(hb + (size_t)(i>>3)*HC + h*CPH);
  uint4 A = p[0], B = p[1];
  const float* as = asrc + h*CPH;
  const float* ad = adst + h*CPH;
  float c[16] = { blo(A.x), bhi(A.x), blo(A.y), bhi(A.y), blo(A.z), bhi(A.z), blo(A.w), bhi(A.w),
                  blo(B.x), bhi(B.x), blo(B.y), bhi(B.y), blo(B.z), bhi(B.z), blo(B.w), bhi(B.w) };
  float s0 = 0.f, s1 = 0.f;
  #pragma unroll
  for (int q = 0; q < 16; ++q){ s0 += c[q]*as[q]; s1 += c[q]*ad[q]; }
  ls[i] = s0; ld[i] = s1;
}

// ---------- attention + aggregation: one wave per destination node ----------
template<bool OBF>
__global__ void k_agg(const int* __restrict__ off, const int* __restrict__ csrc,
                      const unsigned short* __restrict__ hb, const float* __restrict__ ls,
                      const float* __restrict__ ld, const float* __restrict__ bias,
                      void* __restrict__ outv){
  int wid = threadIdx.x >> 6, lane = threadIdx.x & 63;
  int n = blockIdx.x*4 + wid;
  if (n >= N_NODES) return;
  int rs = __builtin_amdgcn_readfirstlane(off[n]);
  int re = __builtin_amdgcn_readfirstlane(off[n+1]);
  int h = lane >> 3;
  float ldh = ld[n*8 + h];
  const ushort2* hb2 = (const ushort2*)hb;
  float acc0 = 0.f, acc1 = 0.f, dsum = 0.f;
  int e = rs;
  for (; e + 4 <= re; e += 4){
    int s0 = __builtin_amdgcn_readfirstlane(csrc[e+0]);
    int s1 = __builtin_amdgcn_readfirstlane(csrc[e+1]);
    int s2 = __builtin_amdgcn_readfirstlane(csrc[e+2]);
    int s3 = __builtin_amdgcn_readfirstlane(csrc[e+3]);
    float g0 = ls[s0*8+h], g1 = ls[s1*8+h], g2 = ls[s2*8+h], g3 = ls[s3*8+h];
    ushort2 v0 = hb2[(size_t)s0*64 + lane];
    ushort2 v1 = hb2[(size_t)s1*64 + lane];
    ushort2 v2 = hb2[(size_t)s2*64 + lane];
    ushort2 v3 = hb2[(size_t)s3*64 + lane];
    float x0 = __expf(leaky(g0 + ldh));
    float x1 = __expf(leaky(g1 + ldh));
    float x2 = __expf(leaky(g2 + ldh));
    float x3 = __expf(leaky(g3 + ldh));
    acc0 += x0*bf2f(v0.x); acc1 += x0*bf2f(v0.y);
    acc0 += x1*bf2f(v1.x); acc1 += x1*bf2f(v1.y);
    acc0 += x2*bf2f(v2.x); acc1 += x2*bf2f(v2.y);
    acc0 += x3*bf2f(v3.x); acc1 += x3*bf2f(v3.y);
    dsum += x0 + x1 + x2 + x3;
  }
  for (; e < re; ++e){
    int s = __builtin_amdgcn_readfirstlane(csrc[e]);
    float ex = __expf(leaky(ls[s*8+h] + ldh));
    ushort2 v = hb2[(size_t)s*64 + lane];
    acc0 += ex*bf2f(v.x); acc1 += ex*bf2f(v.y);
    dsum += ex;
  }
  float inv = 1.f/fmaxf(dsum, 1e-16f);
  int c0 = lane*2;
  float o0 = fmaxf(acc0*inv + bias[c0],   0.f);
  float o1 = fmaxf(acc1*inv + bias[c0+1], 0.f);
  if (OBF){
    ushort2 o; o.x = f2bf(o0); o.y = f2bf(o1);
    ((ushort2*)outv)[(size_t)n*64 + lane] = o;
  } else {
    ((float2*)outv)[(size_t)n*64 + lane] = make_float2(o0, o1);
  }
}

// ---------- pooling + classify fused ----------
__global__ void k_poolcls(const float* __restrict__ h, const int* __restrict__ goff,
                          const float* __restrict__ lw, const float* __restrict__ lb,
                          float* __restrict__ out){
  __shared__ float sh[4][HC];
  int g = blockIdx.x;
  int t = threadIdx.x, lane = t & 63, wv = t >> 6;
  int s = goff[g], epos = goff[g+1];
  float a0 = 0.f, a1 = 0.f;
  for (int n = s + wv; n < epos; n += 4){
    float2 v = ((const float2*)h)[(size_t)n*64 + lane];
    a0 += v.x; a1 += v.y;
  }
  sh[wv][lane*2] = a0; sh[wv][lane*2+1] = a1;
  __syncthreads();
  if (wv == 0){
    int c0 = lane*2;
    float p0 = sh[0][c0] + sh[1][c0] + sh[2][c0] + sh[3][c0];
    float p1 = sh[0][c0+1] + sh[1][c0+1] + sh[2][c0+1] + sh[3][c0+1];
    int cntg = epos - s;
    float invc = 1.f/fmaxf((float)cntg, 1.f);
    float v0 = p0*invc, v1 = p1*invc;
    float l0 = v0*lw[c0*2+0] + v1*lw[(c0+1)*2+0];
    float l1 = v0*lw[c0*2+1] + v1*lw[(c0+1)*2+1];
    #pragma unroll
    for (int o = 32; o >= 1; o >>= 1){ l0 += __shfl_xor(l0,o,64); l1 += __shfl_xor(l1,o,64); }
    if (lane == 0){
      l0 += lb[0]; l1 += lb[1];
      float m = fmaxf(l0,l1);
      float e0 = __expf(l0-m), e1 = __expf(l1-m);
      float si = e0 + e1;
      out[g*2]   = e0/si;
      out[g*2+1] = e1/si;
    }
  }
}

extern "C" void kernel_launch(void* const* d_in, const int* in_sizes, int n_in,
                              void* d_out, int out_size, void* d_ws, size_t ws_size,
                              hipStream_t stream){
  const float* x   = (const float*)d_in[0];
  const int*   ei  = (const int*)d_in[1];
  const int*   bat = (const int*)d_in[2];
  const float* W1  = (const float*)d_in[3];
  const float* a1s = (const float*)d_in[4];
  const float* a1d = (const float*)d_in[5];
  const float* b1  = (const float*)d_in[6];
  const float* W2  = (const float*)d_in[7];
  const float* a2s = (const float*)d_in[8];
  const float* a2d = (const float*)d_in[9];
  const float* b2  = (const float*)d_in[10];
  const float* lw  = (const float*)d_in[11];
  const float* lb  = (const float*)d_in[12];
  float* out = (float*)d_out;

  char* w = (char*)d_ws;
  auto alloc = [&](size_t bytes)->void*{ void* p = (void*)w; w += (bytes + 511) & ~size_t(511); return p; };
  int* cnt    = (int*)alloc((size_t)N_NODES*4);
  int* off    = (int*)alloc((size_t)(N_NODES+1)*4);
  int* csrc   = (int*)alloc((size_t)E_TOTAL*4);
  int* bsum   = (int*)alloc((size_t)(NB_SCAN+1)*4);
  int* goff   = (int*)alloc((size_t)(N_GRAPHS+1)*4);
  int* gpos   = (int*)alloc((size_t)NBUK*4);
  unsigned short* w2t  = (unsigned short*)alloc((size_t)HC*HC*2);
  unsigned short* hbf  = (unsigned short*)alloc((size_t)N_NODES*HC*2);
  unsigned short* hbf2 = (unsigned short*)alloc((size_t)N_NODES*HC*2);
  float* hbuf = (float*)alloc((size_t)N_NODES*HC*4);       // aliased as gbin during CSR build
  float* lsb  = (float*)alloc((size_t)N_NODES*HEADS*4);
  float* ldb  = (float*)alloc((size_t)N_NODES*HEADS*4);
  unsigned* gbin = (unsigned*)hbuf;                        // 196*12288*4 = 9.6 MB < 51.2 MB

  hipMemsetAsync(gpos, 0, (size_t)NBUK*4, stream);

  // CSR build (bucketed)
  k_bin     <<<NBIN_BLK,BIN_TPB,0,stream>>>(ei, gpos, gbin);
  k_bcnt    <<<NBUK,256,0,stream>>>(gpos, gbin, cnt);
  k_scan1   <<<NB_SCAN,SCAN_B,0,stream>>>(cnt, off, bsum);
  k_scan2   <<<1,256,0,stream>>>(bsum, NB_SCAN);
  k_scan3   <<<(N_NODES+255)/256,256,0,stream>>>(off, bsum);
  k_bscatter<<<NBUK,256,0,stream>>>(gpos, gbin, off, csrc);
  k_goff    <<<(N_NODES+255)/256,256,0,stream>>>(bat, goff);
  k_wconv   <<<(HC*HC+255)/256,256,0,stream>>>(W2, w2t);

  // layer 1
  k_gemm1 <<<(N_NODES*64+255)/256,256,0,stream>>>(x, W1, hbf);
  k_logits<<<(N_NODES*HEADS+255)/256,256,0,stream>>>(hbf, a1s, a1d, lsb, ldb);
  k_agg<true> <<<(N_NODES+3)/4,256,0,stream>>>(off, csrc, hbf, lsb, ldb, b1, (void*)hbf2);
  // layer 2
  k_gemm2_mfma<<<(N_NODES+63)/64,256,0,stream>>>(hbf2, w2t, hbf);
  k_logits<<<(N_NODES*HEADS+255)/256,256,0,stream>>>(hbf, a2s, a2d, lsb, ldb);
  k_agg<false><<<(N_NODES+3)/4,256,0,stream>>>(off, csrc, hbf, lsb, ldb, b2, (void*)hbuf);

  // pooling + classifier
  k_poolcls<<<N_GRAPHS,256,0,stream>>>(hbuf, goff, lw, lb, out);
}